// Round 5
// baseline (374.620 us; speedup 1.0000x reference)
//
#include <hip/hip_runtime.h>
#include <hip/hip_bf16.h>
#include <hip/hip_fp16.h>

typedef _Float16 f16x8 __attribute__((ext_vector_type(8)));
typedef _Float16 f16x4 __attribute__((ext_vector_type(4)));
typedef float f32x4 __attribute__((ext_vector_type(4)));

#define T_TOK 8192
#define DIM   1024
#define FF    4096
#define NE    8
#define CAP   1024

// ---------------------------------------------------------------------------
// async global->LDS 16B copy. LDS dest = wave-uniform base + lane*16 (HW);
// global src is per-lane.
// ---------------------------------------------------------------------------
__device__ __forceinline__ void cp16(_Float16* lds, const _Float16* g) {
  __builtin_amdgcn_global_load_lds(
      (const __attribute__((address_space(1))) unsigned int*)(const void*)g,
      (__attribute__((address_space(3))) unsigned int*)(void*)lds, 16, 0, 0);
}

// ---------------------------------------------------------------------------
// Router (proven)
// ---------------------------------------------------------------------------
__global__ __launch_bounds__(256) void moe_router(
    const float* __restrict__ x, const float* __restrict__ Wr,
    int* __restrict__ top, float* __restrict__ topw)
{
  __shared__ float sWr[DIM * 9];
  const int tid = threadIdx.x;
  for (int i = tid; i < DIM * NE; i += 256) {
    int d = i >> 3, e = i & 7;
    sWr[d * 9 + e] = Wr[i];
  }
  __syncthreads();
  const int lane = tid & 63, w = tid >> 6;
  for (int t = 0; t < 4; ++t) {
    const int token = blockIdx.x * 16 + w * 4 + t;
    float acc[8] = {0.f, 0.f, 0.f, 0.f, 0.f, 0.f, 0.f, 0.f};
    for (int j = 0; j < 16; ++j) {
      float xv = x[(size_t)token * DIM + j * 64 + lane];
      const float* wr = &sWr[(j * 64 + lane) * 9];
#pragma unroll
      for (int e = 0; e < 8; ++e) acc[e] += xv * wr[e];
    }
#pragma unroll
    for (int e = 0; e < 8; ++e) {
#pragma unroll
      for (int off = 32; off > 0; off >>= 1)
        acc[e] += __shfl_xor(acc[e], off, 64);
    }
    if (lane == 0) {
      float m = acc[0];
#pragma unroll
      for (int e = 1; e < 8; ++e) m = fmaxf(m, acc[e]);
      float s = 0.f;
#pragma unroll
      for (int e = 0; e < 8; ++e) s += expf(acc[e] - m);
      int bi = 0; float bv = acc[0];
#pragma unroll
      for (int e = 1; e < 8; ++e) { if (acc[e] > bv) { bv = acc[e]; bi = e; } }
      top[token]  = bi;
      topw[token] = 1.0f / s;
    }
  }
}

// ---------------------------------------------------------------------------
// Order-preserving dispatch (proven, 1024 thr)
// ---------------------------------------------------------------------------
__global__ __launch_bounds__(1024) void moe_scan(
    const int* __restrict__ top, int* __restrict__ idx)
{
  __shared__ int running[8];
  __shared__ int wcnt[16][8];
  __shared__ int wpre[16][8];
  __shared__ int cbase[8];
  const int tid = threadIdx.x, lane = tid & 63, w = tid >> 6;
  for (int i = tid; i < NE * CAP; i += 1024) idx[i] = T_TOK;
  if (tid < 8) running[tid] = 0;
  __syncthreads();
  for (int chunk = 0; chunk < T_TOK / 1024; ++chunk) {
    const int tok = chunk * 1024 + tid;
    const int e = top[tok];
    unsigned long long mymask = 0ull;
#pragma unroll
    for (int ee = 0; ee < 8; ++ee) {
      unsigned long long m = __ballot(e == ee);
      if (ee == e) mymask = m;
      if (lane == ee) wcnt[w][ee] = __builtin_popcountll(m);
    }
    const int rankw = __builtin_popcountll(mymask & ((1ull << lane) - 1ull));
    __syncthreads();
    if (tid < 8) {
      int s = 0;
#pragma unroll
      for (int ww = 0; ww < 16; ++ww) { wpre[ww][tid] = s; s += wcnt[ww][tid]; }
      cbase[tid] = running[tid];
      running[tid] += s;
    }
    __syncthreads();
    const int rank = cbase[e] + wpre[w][e] + rankw;
    if (rank < CAP) idx[e * CAP + rank] = tok;
  }
}

// ---------------------------------------------------------------------------
// Gathered-x fp16 image (proven)
// ---------------------------------------------------------------------------
__global__ __launch_bounds__(256) void xg_pass(
    const float* __restrict__ x, const int* __restrict__ idx,
    _Float16* __restrict__ img)
{
  const int tid = threadIdx.x, bid = blockIdx.x;
  const int kt = bid & 15, mt = (bid >> 4) & 3, e = bid >> 6;
  const int tok = idx[e * CAP + mt * 256 + tid];
  _Float16* dst = img + (size_t)((e * 4 + mt) * 16 + kt) * 16384 + (size_t)tid * 64;
  if (tok < T_TOK) {
    const f32x4* src = (const f32x4*)(x + (size_t)tok * DIM + kt * 64);
    f32x4 v[16];
#pragma unroll
    for (int i = 0; i < 16; ++i) v[i] = src[i];
#pragma unroll
    for (int g = 0; g < 8; ++g) {
      f16x8 h;
#pragma unroll
      for (int c = 0; c < 4; ++c) {
        h[c]     = (_Float16)v[2 * g][c];
        h[4 + c] = (_Float16)v[2 * g + 1][c];
      }
      *(f16x8*)(dst + ((g ^ (tid & 7)) * 8)) = h;
    }
  } else {
    f16x8 z = {};
#pragma unroll
    for (int g = 0; g < 8; ++g) *(f16x8*)(dst + g * 8) = z;
  }
}

// ---------------------------------------------------------------------------
// W fp32 [K][N] -> fp16 image tiles [n BN][k 64], granule g at g ^ (n&7)
// (proven)
// ---------------------------------------------------------------------------
template<int BN, int NKT, int NNT, int NFULL>
__global__ __launch_bounds__(256) void w_image(
    const float* __restrict__ W, _Float16* __restrict__ img)
{
  __shared__ _Float16 sT[64 * BN];
  const int tid = threadIdx.x, bid = blockIdx.x;
  const int kt = bid % NKT, nt = (bid / NKT) % NNT, e = bid / (NKT * NNT);
  const float* src = W + (size_t)e * (NKT * 64) * NFULL + (size_t)(kt * 64) * NFULL + nt * BN;
  constexpr int CPT = (64 * BN / 4) / 256;
#pragma unroll
  for (int i = 0; i < CPT; ++i) {
    const int q = i * 256 + tid;
    const int row = q / (BN / 4), c4 = q % (BN / 4);
    f32x4 u = *(const f32x4*)(src + (size_t)row * NFULL + c4 * 4);
    f16x4 h;
#pragma unroll
    for (int c = 0; c < 4; ++c) h[c] = (_Float16)u[c];
    *(f16x4*)&sT[row * BN + c4 * 4] = h;
  }
  __syncthreads();
  _Float16* dst = img + (size_t)bid * (BN * 64);
  constexpr int GPT = BN * 8 / 256;
  const int n = tid % BN, gb = (tid / BN) * GPT;
#pragma unroll
  for (int i = 0; i < GPT; ++i) {
    const int gpos = gb + i, g = gpos ^ (n & 7);
    f16x8 h;
#pragma unroll
    for (int j = 0; j < 8; ++j) h[j] = sT[(g * 8 + j) * BN + n];
    *(f16x8*)(dst + (size_t)n * 64 + gpos * 8) = h;
  }
}

// ---------------------------------------------------------------------------
// GEMM1 8p: hidden = relu(xg @ W1img + b1). 256x128xBK64, 512 thr (8 waves
// 4Mx2N), TRIPLE-buffered LDS (144 KB), counted vmcnt(6), raw barriers,
// 1 barrier per K-tile, setprio around MFMA. 1 block/CU.
// ---------------------------------------------------------------------------
__global__ __launch_bounds__(512, 2) void gemm1_8p(
    const _Float16* __restrict__ xg, const _Float16* __restrict__ w1img,
    const float* __restrict__ b1, _Float16* __restrict__ hidden)
{
  __shared__ _Float16 As[3][16384];  // 96 KB : 256 rows x 64 k
  __shared__ _Float16 Bs[3][8192];   // 48 KB : 128 n x 64 k
  const int tid = threadIdx.x, lane = tid & 63, w = tid >> 6;
  const int wm = w >> 1, wn = w & 1;
  const int l15 = lane & 15, l4 = lane >> 4;
  const int bid = blockIdx.x;
  const int e   = bid >> 7;
  const int low = bid & 127;
  const int nt  = ((low & 7) << 2) | ((low >> 3) & 3);  // 0..31 (128-col F tile)
  const int mt  = low >> 5;                             // 0..3  (256-row tile)

  const _Float16* aT = xg + (size_t)((e * 4 + mt) * 16) * 16384;                  // +kt*16384
  const _Float16* bT = w1img + (size_t)((e * 16 + (nt >> 1)) * 16) * 16384
                       + (size_t)(nt & 1) * 8192;                                 // +kt*16384

  f32x4 acc[4][4];
#pragma unroll
  for (int i = 0; i < 4; ++i)
#pragma unroll
    for (int j = 0; j < 4; ++j) acc[i][j] = (f32x4){0.f, 0.f, 0.f, 0.f};

#define G1_STAGE(kt_, buf_)                                                    \
  {                                                                            \
    const _Float16* as_ = aT + (size_t)(kt_) * 16384 + w * 2048 + lane * 8;    \
    const _Float16* bs_ = bT + (size_t)(kt_) * 16384 + w * 1024 + lane * 8;    \
    _Pragma("unroll")                                                          \
    for (int i_ = 0; i_ < 4; ++i_)                                             \
      cp16(&As[buf_][w * 2048 + i_ * 512], as_ + i_ * 512);                    \
    _Pragma("unroll")                                                          \
    for (int i_ = 0; i_ < 2; ++i_)                                             \
      cp16(&Bs[buf_][w * 1024 + i_ * 512], bs_ + i_ * 512);                    \
  }

  G1_STAGE(0, 0);
  G1_STAGE(1, 1);

  int cur = 0;
  for (int kt = 0; kt < 16; ++kt) {
    if (kt == 15) { asm volatile("s_waitcnt vmcnt(0)" ::: "memory"); }
    else          { asm volatile("s_waitcnt vmcnt(6)" ::: "memory"); }
    __builtin_amdgcn_s_barrier();
    if (kt + 2 < 16) {
      const int sb = (cur >= 1) ? (cur - 1) : 2;   // (kt+2)%3
      G1_STAGE(kt + 2, sb);
    }
#pragma unroll
    for (int ks = 0; ks < 2; ++ks) {
      const int gq = ks * 4 + l4;
      f16x8 af[4], bf[4];
#pragma unroll
      for (int fm = 0; fm < 4; ++fm) {
        const int m = wm * 64 + fm * 16 + l15;
        af[fm] = *(const f16x8*)&As[cur][m * 64 + (gq ^ (m & 7)) * 8];
      }
#pragma unroll
      for (int fn = 0; fn < 4; ++fn) {
        const int n = wn * 64 + fn * 16 + l15;
        bf[fn] = *(const f16x8*)&Bs[cur][n * 64 + (gq ^ (n & 7)) * 8];
      }
      __builtin_amdgcn_s_setprio(1);
#pragma unroll
      for (int fm = 0; fm < 4; ++fm)
#pragma unroll
        for (int fn = 0; fn < 4; ++fn)
          acc[fm][fn] = __builtin_amdgcn_mfma_f32_16x16x32_f16(af[fm], bf[fn], acc[fm][fn], 0, 0, 0);
      __builtin_amdgcn_s_setprio(0);
    }
    cur = (cur == 2) ? 0 : cur + 1;
  }

  // ---- epilogue: LDS-bounce transpose, relu(acc+b1) -> hidden image ----
  __builtin_amdgcn_s_barrier();     // all waves done reading K-loop LDS
  float* sw = (float*)&As[0][0] + (size_t)w * 2048;   // 8 KB scratch per wave
  const int ftile = nt * 2 + wn;                       // 0..63
  const int mt128 = mt * 2 + (wm >> 1);                // 0..7
  const size_t tbase = ((size_t)((e * 8 + mt128) * 64) + ftile) * 8192;
  const int fbase = nt * 128 + wn * 64;
#pragma unroll
  for (int fm = 0; fm < 4; ++fm) {
#pragma unroll
    for (int fn = 0; fn < 4; ++fn) {
      const int floc = fn * 16 + l15;
      const float bb = b1[e * FF + fbase + floc];
      f32x4 v;
#pragma unroll
      for (int r = 0; r < 4; ++r) v[r] = fmaxf(acc[fm][fn][r] + bb, 0.f);
      *(f32x4*)&sw[floc * 17 + l4 * 4] = v;
    }
    const int p = l15;
    const int mrow = (wm & 1) * 64 + fm * 16 + p;      // row within 128-subtile
#pragma unroll
    for (int it = 0; it < 2; ++it) {
      const int g = it * 4 + l4;
      f16x8 h;
#pragma unroll
      for (int j = 0; j < 8; ++j) h[j] = (_Float16)sw[(g * 8 + j) * 17 + p];
      *(f16x8*)&hidden[tbase + (size_t)mrow * 64 + (g ^ (mrow & 7)) * 8] = h;
    }
  }
#undef G1_STAGE
}

// ---------------------------------------------------------------------------
// GEMM2 8p: out[tok] = (hidden @ W2img + b2) * topw. Same schedule.
// bid&7 = e -> per-XCD working set = one expert's K-synchronized slice.
// ---------------------------------------------------------------------------
__global__ __launch_bounds__(512, 2) void gemm2_8p(
    const _Float16* __restrict__ hidden, const _Float16* __restrict__ w2img,
    const float* __restrict__ b2, const int* __restrict__ idx,
    const float* __restrict__ topw, float* __restrict__ out)
{
  __shared__ _Float16 As[3][16384];
  __shared__ _Float16 Bs[3][8192];
  const int tid = threadIdx.x, lane = tid & 63, w = tid >> 6;
  const int wm = w >> 1, wn = w & 1;
  const int l15 = lane & 15, l4 = lane >> 4;
  const int bid = blockIdx.x;
  const int e  = bid & 7;
  const int s  = bid >> 3;       // 0..31
  const int mt = s >> 3;         // 0..3 (256-row tile)
  const int nt = s & 7;          // 0..7 (128-col D tile)

  // A halves: hidden subtiles (e, mt128 = 2mt+h), each [128 rows][64 f] per kt
  const _Float16* aT0 = hidden + (size_t)((e * 8 + mt * 2) * 64) * 8192;       // +kt*8192
  const _Float16* aT1 = aT0 + (size_t)64 * 8192;
  const _Float16* bT  = w2img + (size_t)((e * 8 + nt) * 64) * 8192;            // +kt*8192

  f32x4 acc[4][4];
#pragma unroll
  for (int i = 0; i < 4; ++i)
#pragma unroll
    for (int j = 0; j < 4; ++j) acc[i][j] = (f32x4){0.f, 0.f, 0.f, 0.f};

#define G2_STAGE(kt_, buf_)                                                    \
  {                                                                            \
    const _Float16* a0_ = aT0 + (size_t)(kt_) * 8192 + w * 1024 + lane * 8;    \
    const _Float16* a1_ = aT1 + (size_t)(kt_) * 8192 + w * 1024 + lane * 8;    \
    const _Float16* bs_ = bT  + (size_t)(kt_) * 8192 + w * 1024 + lane * 8;    \
    _Pragma("unroll")                                                          \
    for (int i_ = 0; i_ < 2; ++i_)                                             \
      cp16(&As[buf_][w * 1024 + i_ * 512], a0_ + i_ * 512);                    \
    _Pragma("unroll")                                                          \
    for (int i_ = 0; i_ < 2; ++i_)                                             \
      cp16(&As[buf_][8192 + w * 1024 + i_ * 512], a1_ + i_ * 512);             \
    _Pragma("unroll")                                                          \
    for (int i_ = 0; i_ < 2; ++i_)                                             \
      cp16(&Bs[buf_][w * 1024 + i_ * 512], bs_ + i_ * 512);                    \
  }

  G2_STAGE(0, 0);
  G2_STAGE(1, 1);

  int cur = 0;
  for (int kt = 0; kt < 64; ++kt) {
    if (kt == 63) { asm volatile("s_waitcnt vmcnt(0)" ::: "memory"); }
    else          { asm volatile("s_waitcnt vmcnt(6)" ::: "memory"); }
    __builtin_amdgcn_s_barrier();
    if (kt + 2 < 64) {
      const int sb = (cur >= 1) ? (cur - 1) : 2;   // (kt+2)%3
      G2_STAGE(kt + 2, sb);
    }
#pragma unroll
    for (int ks = 0; ks < 2; ++ks) {
      const int gq = ks * 4 + l4;
      f16x8 af[4], bf[4];
#pragma unroll
      for (int fm = 0; fm < 4; ++fm) {
        const int m = wm * 64 + fm * 16 + l15;
        af[fm] = *(const f16x8*)&As[cur][m * 64 + (gq ^ (m & 7)) * 8];
      }
#pragma unroll
      for (int fn = 0; fn < 4; ++fn) {
        const int n = wn * 64 + fn * 16 + l15;
        bf[fn] = *(const f16x8*)&Bs[cur][n * 64 + (gq ^ (n & 7)) * 8];
      }
      __builtin_amdgcn_s_setprio(1);
#pragma unroll
      for (int fm = 0; fm < 4; ++fm)
#pragma unroll
        for (int fn = 0; fn < 4; ++fn)
          acc[fm][fn] = __builtin_amdgcn_mfma_f32_16x16x32_f16(af[fm], bf[fn], acc[fm][fn], 0, 0, 0);
      __builtin_amdgcn_s_setprio(0);
    }
    cur = (cur == 2) ? 0 : cur + 1;
  }

  // epilogue: scatter (acc + b2) * topw to token rows
  int   toks[4][4];
  float wgts[4][4];
#pragma unroll
  for (int fm = 0; fm < 4; ++fm)
#pragma unroll
    for (int r = 0; r < 4; ++r) {
      const int row = mt * 256 + wm * 64 + fm * 16 + l4 * 4 + r;
      const int tk = idx[e * CAP + row];
      toks[fm][r] = tk;
      wgts[fm][r] = (tk < T_TOK) ? topw[tk] : 0.f;
    }
#pragma unroll
  for (int fn = 0; fn < 4; ++fn) {
    const int dcol = nt * 128 + wn * 64 + fn * 16 + l15;
    const float bb = b2[e * DIM + dcol];
#pragma unroll
    for (int fm = 0; fm < 4; ++fm)
#pragma unroll
      for (int r = 0; r < 4; ++r) {
        const int tk = toks[fm][r];
        if (tk < T_TOK)
          out[(size_t)tk * DIM + dcol] = (acc[fm][fn][r] + bb) * wgts[fm][r];
      }
  }
#undef G2_STAGE
}

// ---------------------------------------------------------------------------
extern "C" void kernel_launch(void* const* d_in, const int* in_sizes, int n_in,
                              void* d_out, int out_size, void* d_ws, size_t ws_size,
                              hipStream_t stream)
{
  const float* x  = (const float*)d_in[0];
  const float* Wr = (const float*)d_in[1];
  const float* W1 = (const float*)d_in[2];
  const float* b1 = (const float*)d_in[3];
  const float* W2 = (const float*)d_in[4];
  const float* b2 = (const float*)d_in[5];
  float* out = (float*)d_out;
  char* ws = (char*)d_ws;

  const size_t HID  = 67108864ull;  // hidden image fp16
  const size_t WIMG = 67108864ull;  // shared W1/W2 image buffer
  const size_t XG   = 16777216ull;  // gathered-x image fp16

  _Float16* hidden = (_Float16*)ws;
  _Float16* wimg   = (_Float16*)(ws + HID);
  _Float16* xg     = (_Float16*)(ws + HID + WIMG);
  int*   idx  = (int*)(ws + HID + WIMG + XG);
  int*   top  = idx + 8192;
  float* topw = (float*)(top + 8192);

  hipMemsetAsync(d_out, 0, (size_t)T_TOK * DIM * sizeof(float), stream);
  moe_router<<<T_TOK / 16, 256, 0, stream>>>(x, Wr, top, topw);
  moe_scan<<<1, 1024, 0, stream>>>(top, idx);
  xg_pass<<<NE * 4 * 16, 256, 0, stream>>>(x, idx, xg);
  w_image<256, 16, 16, FF><<<NE * 16 * 16, 256, 0, stream>>>(W1, wimg);
  gemm1_8p<<<NE * 4 * 32, 512, 0, stream>>>(xg, wimg, b1, hidden);
  w_image<128, 64, 8, DIM><<<NE * 8 * 64, 256, 0, stream>>>(W2, wimg);
  gemm2_8p<<<NE * 4 * 8, 512, 0, stream>>>(hidden, wimg, b2, idx, topw, out);
}

// Round 6
// 309.706 us; speedup vs baseline: 1.2096x; 1.2096x over previous
//
#include <hip/hip_runtime.h>
#include <hip/hip_bf16.h>
#include <hip/hip_fp16.h>

typedef _Float16 f16x8 __attribute__((ext_vector_type(8)));
typedef _Float16 f16x4 __attribute__((ext_vector_type(4)));
typedef float f32x4 __attribute__((ext_vector_type(4)));

#define T_TOK 8192
#define DIM   1024
#define FF    4096
#define NE    8
#define CAP   1024

// ---------------------------------------------------------------------------
// async global->LDS 16B copy. LDS dest = wave-uniform base + lane*16 (HW);
// global src is per-lane.
// ---------------------------------------------------------------------------
__device__ __forceinline__ void cp16(_Float16* lds, const _Float16* g) {
  __builtin_amdgcn_global_load_lds(
      (const __attribute__((address_space(1))) unsigned int*)(const void*)g,
      (__attribute__((address_space(3))) unsigned int*)(void*)lds, 16, 0, 0);
}

// ---------------------------------------------------------------------------
// Router (proven)
// ---------------------------------------------------------------------------
__global__ __launch_bounds__(256) void moe_router(
    const float* __restrict__ x, const float* __restrict__ Wr,
    int* __restrict__ top, float* __restrict__ topw)
{
  __shared__ float sWr[DIM * 9];
  const int tid = threadIdx.x;
  for (int i = tid; i < DIM * NE; i += 256) {
    int d = i >> 3, e = i & 7;
    sWr[d * 9 + e] = Wr[i];
  }
  __syncthreads();
  const int lane = tid & 63, w = tid >> 6;
  for (int t = 0; t < 4; ++t) {
    const int token = blockIdx.x * 16 + w * 4 + t;
    float acc[8] = {0.f, 0.f, 0.f, 0.f, 0.f, 0.f, 0.f, 0.f};
    for (int j = 0; j < 16; ++j) {
      float xv = x[(size_t)token * DIM + j * 64 + lane];
      const float* wr = &sWr[(j * 64 + lane) * 9];
#pragma unroll
      for (int e = 0; e < 8; ++e) acc[e] += xv * wr[e];
    }
#pragma unroll
    for (int e = 0; e < 8; ++e) {
#pragma unroll
      for (int off = 32; off > 0; off >>= 1)
        acc[e] += __shfl_xor(acc[e], off, 64);
    }
    if (lane == 0) {
      float m = acc[0];
#pragma unroll
      for (int e = 1; e < 8; ++e) m = fmaxf(m, acc[e]);
      float s = 0.f;
#pragma unroll
      for (int e = 0; e < 8; ++e) s += expf(acc[e] - m);
      int bi = 0; float bv = acc[0];
#pragma unroll
      for (int e = 1; e < 8; ++e) { if (acc[e] > bv) { bv = acc[e]; bi = e; } }
      top[token]  = bi;
      topw[token] = 1.0f / s;
    }
  }
}

// ---------------------------------------------------------------------------
// Order-preserving dispatch (proven, 1024 thr)
// ---------------------------------------------------------------------------
__global__ __launch_bounds__(1024) void moe_scan(
    const int* __restrict__ top, int* __restrict__ idx)
{
  __shared__ int running[8];
  __shared__ int wcnt[16][8];
  __shared__ int wpre[16][8];
  __shared__ int cbase[8];
  const int tid = threadIdx.x, lane = tid & 63, w = tid >> 6;
  for (int i = tid; i < NE * CAP; i += 1024) idx[i] = T_TOK;
  if (tid < 8) running[tid] = 0;
  __syncthreads();
  for (int chunk = 0; chunk < T_TOK / 1024; ++chunk) {
    const int tok = chunk * 1024 + tid;
    const int e = top[tok];
    unsigned long long mymask = 0ull;
#pragma unroll
    for (int ee = 0; ee < 8; ++ee) {
      unsigned long long m = __ballot(e == ee);
      if (ee == e) mymask = m;
      if (lane == ee) wcnt[w][ee] = __builtin_popcountll(m);
    }
    const int rankw = __builtin_popcountll(mymask & ((1ull << lane) - 1ull));
    __syncthreads();
    if (tid < 8) {
      int s = 0;
#pragma unroll
      for (int ww = 0; ww < 16; ++ww) { wpre[ww][tid] = s; s += wcnt[ww][tid]; }
      cbase[tid] = running[tid];
      running[tid] += s;
    }
    __syncthreads();
    const int rank = cbase[e] + wpre[w][e] + rankw;
    if (rank < CAP) idx[e * CAP + rank] = tok;
  }
}

// ---------------------------------------------------------------------------
// Gathered-x fp16 image (proven)
// ---------------------------------------------------------------------------
__global__ __launch_bounds__(256) void xg_pass(
    const float* __restrict__ x, const int* __restrict__ idx,
    _Float16* __restrict__ img)
{
  const int tid = threadIdx.x, bid = blockIdx.x;
  const int kt = bid & 15, mt = (bid >> 4) & 3, e = bid >> 6;
  const int tok = idx[e * CAP + mt * 256 + tid];
  _Float16* dst = img + (size_t)((e * 4 + mt) * 16 + kt) * 16384 + (size_t)tid * 64;
  if (tok < T_TOK) {
    const f32x4* src = (const f32x4*)(x + (size_t)tok * DIM + kt * 64);
    f32x4 v[16];
#pragma unroll
    for (int i = 0; i < 16; ++i) v[i] = src[i];
#pragma unroll
    for (int g = 0; g < 8; ++g) {
      f16x8 h;
#pragma unroll
      for (int c = 0; c < 4; ++c) {
        h[c]     = (_Float16)v[2 * g][c];
        h[4 + c] = (_Float16)v[2 * g + 1][c];
      }
      *(f16x8*)(dst + ((g ^ (tid & 7)) * 8)) = h;
    }
  } else {
    f16x8 z = {};
#pragma unroll
    for (int g = 0; g < 8; ++g) *(f16x8*)(dst + g * 8) = z;
  }
}

// ---------------------------------------------------------------------------
// W fp32 [K][N] -> fp16 image tiles [n BN][k 64], granule g at g ^ (n&7)
// (proven)
// ---------------------------------------------------------------------------
template<int BN, int NKT, int NNT, int NFULL>
__global__ __launch_bounds__(256) void w_image(
    const float* __restrict__ W, _Float16* __restrict__ img)
{
  __shared__ _Float16 sT[64 * BN];
  const int tid = threadIdx.x, bid = blockIdx.x;
  const int kt = bid % NKT, nt = (bid / NKT) % NNT, e = bid / (NKT * NNT);
  const float* src = W + (size_t)e * (NKT * 64) * NFULL + (size_t)(kt * 64) * NFULL + nt * BN;
  constexpr int CPT = (64 * BN / 4) / 256;
#pragma unroll
  for (int i = 0; i < CPT; ++i) {
    const int q = i * 256 + tid;
    const int row = q / (BN / 4), c4 = q % (BN / 4);
    f32x4 u = *(const f32x4*)(src + (size_t)row * NFULL + c4 * 4);
    f16x4 h;
#pragma unroll
    for (int c = 0; c < 4; ++c) h[c] = (_Float16)u[c];
    *(f16x4*)&sT[row * BN + c4 * 4] = h;
  }
  __syncthreads();
  _Float16* dst = img + (size_t)bid * (BN * 64);
  constexpr int GPT = BN * 8 / 256;
  const int n = tid % BN, gb = (tid / BN) * GPT;
#pragma unroll
  for (int i = 0; i < GPT; ++i) {
    const int gpos = gb + i, g = gpos ^ (n & 7);
    f16x8 h;
#pragma unroll
    for (int j = 0; j < 8; ++j) h[j] = sT[(g * 8 + j) * BN + n];
    *(f16x8*)(dst + (size_t)n * 64 + gpos * 8) = h;
  }
}

// ---------------------------------------------------------------------------
// GEMM1 (round-4 proven): hidden = relu(xg @ W1img + b1). 128x128xBK64,
// 256 thr (4 waves 2x2), single-buffer 32KB LDS, gload_lds, 3 blocks/CU.
// bid = e*256 + (mt*4+(nt&3))*8 + (nt>>2): each XCD gets an 8mt x 4nt
// rectangle of one expert -> L2 working set 3MB, fully resident.
// ---------------------------------------------------------------------------
__global__ __launch_bounds__(256, 3) void gemm1_big(
    const _Float16* __restrict__ xg, const _Float16* __restrict__ w1img,
    const float* __restrict__ b1, _Float16* __restrict__ hidden)
{
  __shared__ _Float16 As[8192];
  __shared__ _Float16 Bs[8192];
  const int tid = threadIdx.x, lane = tid & 63, w = tid >> 6;
  const int wm = w >> 1, wn = w & 1;
  const int l15 = lane & 15, l4 = lane >> 4;
  const int bid = blockIdx.x;
  const int e   = bid >> 8;
  const int low = bid & 255;
  const int nt  = ((low & 7) << 2) | ((low >> 3) & 3);  // 0..31
  const int mt  = low >> 5;                             // 0..7

  const _Float16* aSrc = xg + ((size_t)(e * 4 + (mt >> 1)) * 16) * 16384
                         + (size_t)(mt & 1) * 8192 + w * 2048 + lane * 8;
  const _Float16* bSrc = w1img + ((size_t)(e * 16 + (nt >> 1)) * 16) * 16384
                         + (size_t)(nt & 1) * 8192 + w * 2048 + lane * 8;

  f32x4 acc[4][4];
#pragma unroll
  for (int i = 0; i < 4; ++i)
#pragma unroll
    for (int j = 0; j < 4; ++j) acc[i][j] = (f32x4){0.f, 0.f, 0.f, 0.f};

  for (int kt = 0; kt < 16; ++kt) {
    __syncthreads();
#pragma unroll
    for (int i = 0; i < 4; ++i) {
      cp16(&As[w * 2048 + i * 512], aSrc + (size_t)kt * 16384 + i * 512);
      cp16(&Bs[w * 2048 + i * 512], bSrc + (size_t)kt * 16384 + i * 512);
    }
    __syncthreads();
#pragma unroll
    for (int ks = 0; ks < 2; ++ks) {
      const int gq = ks * 4 + l4;
      f16x8 af[4], bf[4];
#pragma unroll
      for (int fm = 0; fm < 4; ++fm) {
        const int m = wm * 64 + fm * 16 + l15;
        af[fm] = *(const f16x8*)&As[m * 64 + (gq ^ (m & 7)) * 8];
      }
#pragma unroll
      for (int fn = 0; fn < 4; ++fn) {
        const int n = wn * 64 + fn * 16 + l15;
        bf[fn] = *(const f16x8*)&Bs[n * 64 + (gq ^ (n & 7)) * 8];
      }
#pragma unroll
      for (int fm = 0; fm < 4; ++fm)
#pragma unroll
        for (int fn = 0; fn < 4; ++fn)
          acc[fm][fn] = __builtin_amdgcn_mfma_f32_16x16x32_f16(af[fm], bf[fn], acc[fm][fn], 0, 0, 0);
    }
  }

  // ---- epilogue: LDS-bounce transpose, relu(acc+b1) -> hidden image ----
  __syncthreads();
  float* sw = (float*)((w < 2) ? As : Bs) + (size_t)(w & 1) * 2048;  // 8KB/wave
  const int ftile = nt * 2 + wn;                 // 0..63
  const size_t tbase = ((size_t)((e * 8 + mt) * 64) + ftile) * 8192;
  const int fbase = nt * 128 + wn * 64;
#pragma unroll
  for (int fm = 0; fm < 4; ++fm) {
#pragma unroll
    for (int fn = 0; fn < 4; ++fn) {
      const int floc = fn * 16 + l15;
      const float bb = b1[e * FF + fbase + floc];
      f32x4 v;
#pragma unroll
      for (int r = 0; r < 4; ++r) v[r] = fmaxf(acc[fm][fn][r] + bb, 0.f);
      *(f32x4*)&sw[floc * 17 + l4 * 4] = v;
    }
    const int p = l15;
    const int mrow = wm * 64 + fm * 16 + p;
#pragma unroll
    for (int it = 0; it < 2; ++it) {
      const int g = it * 4 + l4;
      f16x8 h;
#pragma unroll
      for (int j = 0; j < 8; ++j) h[j] = (_Float16)sw[(g * 8 + j) * 17 + p];
      *(f16x8*)&hidden[tbase + (size_t)mrow * 64 + (g ^ (mrow & 7)) * 8] = h;
    }
  }
}

// ---------------------------------------------------------------------------
// GEMM2: out[tok] = (hidden @ W2img + b2) * topw. 128x128xBK64 but with
// 512 thr (8 waves 4Mx2N, wave tile 32x64, acc[2][4]) -> 2 blocks/CU =
// 16 waves/CU to hide the 2-phase stall (round-4 deficit was 8 waves/CU).
// bid = e + 8*(nt*8 + mt): expert pinned to XCD; active K-slice ~256 KB.
// ---------------------------------------------------------------------------
__global__ __launch_bounds__(512, 4) void gemm2_big(
    const _Float16* __restrict__ hidden, const _Float16* __restrict__ w2img,
    const float* __restrict__ b2, const int* __restrict__ idx,
    const float* __restrict__ topw, float* __restrict__ out)
{
  __shared__ _Float16 As[8192];
  __shared__ _Float16 Bs[8192];
  const int tid = threadIdx.x, lane = tid & 63, w = tid >> 6;
  const int wm = w >> 1, wn = w & 1;               // wm 0..3, wn 0..1
  const int l15 = lane & 15, l4 = lane >> 4;
  const int bid = blockIdx.x;
  const int e  = bid & 7;
  const int s  = bid >> 3;       // 0..63
  const int nt = s >> 3;         // 0..7 (128-col D tile)
  const int mt = s & 7;          // 0..7 (128-row tile)

  const _Float16* aSrc = hidden + ((size_t)((e * 8 + mt) * 64)) * 8192 + w * 1024 + lane * 8;
  const _Float16* bSrc = w2img  + ((size_t)((e * 8 + nt) * 64)) * 8192 + w * 1024 + lane * 8;

  f32x4 acc[2][4];
#pragma unroll
  for (int i = 0; i < 2; ++i)
#pragma unroll
    for (int j = 0; j < 4; ++j) acc[i][j] = (f32x4){0.f, 0.f, 0.f, 0.f};

  for (int kt = 0; kt < 64; ++kt) {
    __syncthreads();
#pragma unroll
    for (int i = 0; i < 2; ++i) {
      cp16(&As[w * 1024 + i * 512], aSrc + (size_t)kt * 8192 + i * 512);
      cp16(&Bs[w * 1024 + i * 512], bSrc + (size_t)kt * 8192 + i * 512);
    }
    __syncthreads();
#pragma unroll
    for (int ks = 0; ks < 2; ++ks) {
      const int gq = ks * 4 + l4;
      f16x8 af[2], bf[4];
#pragma unroll
      for (int fm = 0; fm < 2; ++fm) {
        const int m = wm * 32 + fm * 16 + l15;
        af[fm] = *(const f16x8*)&As[m * 64 + (gq ^ (m & 7)) * 8];
      }
#pragma unroll
      for (int fn = 0; fn < 4; ++fn) {
        const int n = wn * 64 + fn * 16 + l15;
        bf[fn] = *(const f16x8*)&Bs[n * 64 + (gq ^ (n & 7)) * 8];
      }
#pragma unroll
      for (int fm = 0; fm < 2; ++fm)
#pragma unroll
        for (int fn = 0; fn < 4; ++fn)
          acc[fm][fn] = __builtin_amdgcn_mfma_f32_16x16x32_f16(af[fm], bf[fn], acc[fm][fn], 0, 0, 0);
    }
  }

  // epilogue: scatter (acc + b2) * topw to token rows
  int   toks[2][4];
  float wgts[2][4];
#pragma unroll
  for (int fm = 0; fm < 2; ++fm)
#pragma unroll
    for (int r = 0; r < 4; ++r) {
      const int row = mt * 128 + wm * 32 + fm * 16 + l4 * 4 + r;
      const int tk = idx[e * CAP + row];
      toks[fm][r] = tk;
      wgts[fm][r] = (tk < T_TOK) ? topw[tk] : 0.f;
    }
#pragma unroll
  for (int fn = 0; fn < 4; ++fn) {
    const int dcol = nt * 128 + wn * 64 + fn * 16 + l15;
    const float bb = b2[e * DIM + dcol];
#pragma unroll
    for (int fm = 0; fm < 2; ++fm)
#pragma unroll
      for (int r = 0; r < 4; ++r) {
        const int tk = toks[fm][r];
        if (tk < T_TOK)
          out[(size_t)tk * DIM + dcol] = (acc[fm][fn][r] + bb) * wgts[fm][r];
      }
  }
}

// ---------------------------------------------------------------------------
extern "C" void kernel_launch(void* const* d_in, const int* in_sizes, int n_in,
                              void* d_out, int out_size, void* d_ws, size_t ws_size,
                              hipStream_t stream)
{
  const float* x  = (const float*)d_in[0];
  const float* Wr = (const float*)d_in[1];
  const float* W1 = (const float*)d_in[2];
  const float* b1 = (const float*)d_in[3];
  const float* W2 = (const float*)d_in[4];
  const float* b2 = (const float*)d_in[5];
  float* out = (float*)d_out;
  char* ws = (char*)d_ws;

  const size_t HID  = 67108864ull;  // hidden image fp16
  const size_t WIMG = 67108864ull;  // shared W1/W2 image buffer
  const size_t XG   = 16777216ull;  // gathered-x image fp16

  _Float16* hidden = (_Float16*)ws;
  _Float16* wimg   = (_Float16*)(ws + HID);
  _Float16* xg     = (_Float16*)(ws + HID + WIMG);
  int*   idx  = (int*)(ws + HID + WIMG + XG);
  int*   top  = idx + 8192;
  float* topw = (float*)(top + 8192);

  hipMemsetAsync(d_out, 0, (size_t)T_TOK * DIM * sizeof(float), stream);
  moe_router<<<T_TOK / 16, 256, 0, stream>>>(x, Wr, top, topw);
  moe_scan<<<1, 1024, 0, stream>>>(top, idx);
  xg_pass<<<NE * 4 * 16, 256, 0, stream>>>(x, idx, xg);
  w_image<256, 16, 16, FF><<<NE * 16 * 16, 256, 0, stream>>>(W1, wimg);
  gemm1_big<<<NE * 8 * 32, 256, 0, stream>>>(xg, wimg, b1, hidden);
  w_image<128, 64, 8, DIM><<<NE * 8 * 64, 256, 0, stream>>>(W2, wimg);
  gemm2_big<<<NE * 8 * 8, 512, 0, stream>>>(hidden, wimg, b2, idx, topw, out);
}

// Round 7
// 308.998 us; speedup vs baseline: 1.2124x; 1.0023x over previous
//
#include <hip/hip_runtime.h>
#include <hip/hip_bf16.h>
#include <hip/hip_fp16.h>

typedef _Float16 f16x8 __attribute__((ext_vector_type(8)));
typedef _Float16 f16x4 __attribute__((ext_vector_type(4)));
typedef float f32x4 __attribute__((ext_vector_type(4)));

#define T_TOK 8192
#define DIM   1024
#define FF    4096
#define NE    8
#define CAP   1024

// ---------------------------------------------------------------------------
// async global->LDS 16B copy. LDS dest = wave-uniform base + lane*16 (HW);
// global src is per-lane.
// ---------------------------------------------------------------------------
__device__ __forceinline__ void cp16(_Float16* lds, const _Float16* g) {
  __builtin_amdgcn_global_load_lds(
      (const __attribute__((address_space(1))) unsigned int*)(const void*)g,
      (__attribute__((address_space(3))) unsigned int*)(void*)lds, 16, 0, 0);
}

// ---------------------------------------------------------------------------
// Router (proven)
// ---------------------------------------------------------------------------
__global__ __launch_bounds__(256) void moe_router(
    const float* __restrict__ x, const float* __restrict__ Wr,
    int* __restrict__ top, float* __restrict__ topw)
{
  __shared__ float sWr[DIM * 9];
  const int tid = threadIdx.x;
  for (int i = tid; i < DIM * NE; i += 256) {
    int d = i >> 3, e = i & 7;
    sWr[d * 9 + e] = Wr[i];
  }
  __syncthreads();
  const int lane = tid & 63, w = tid >> 6;
  for (int t = 0; t < 4; ++t) {
    const int token = blockIdx.x * 16 + w * 4 + t;
    float acc[8] = {0.f, 0.f, 0.f, 0.f, 0.f, 0.f, 0.f, 0.f};
    for (int j = 0; j < 16; ++j) {
      float xv = x[(size_t)token * DIM + j * 64 + lane];
      const float* wr = &sWr[(j * 64 + lane) * 9];
#pragma unroll
      for (int e = 0; e < 8; ++e) acc[e] += xv * wr[e];
    }
#pragma unroll
    for (int e = 0; e < 8; ++e) {
#pragma unroll
      for (int off = 32; off > 0; off >>= 1)
        acc[e] += __shfl_xor(acc[e], off, 64);
    }
    if (lane == 0) {
      float m = acc[0];
#pragma unroll
      for (int e = 1; e < 8; ++e) m = fmaxf(m, acc[e]);
      float s = 0.f;
#pragma unroll
      for (int e = 0; e < 8; ++e) s += expf(acc[e] - m);
      int bi = 0; float bv = acc[0];
#pragma unroll
      for (int e = 1; e < 8; ++e) { if (acc[e] > bv) { bv = acc[e]; bi = e; } }
      top[token]  = bi;
      topw[token] = 1.0f / s;
    }
  }
}

// ---------------------------------------------------------------------------
// Order-preserving dispatch (proven, 1024 thr)
// ---------------------------------------------------------------------------
__global__ __launch_bounds__(1024) void moe_scan(
    const int* __restrict__ top, int* __restrict__ idx)
{
  __shared__ int running[8];
  __shared__ int wcnt[16][8];
  __shared__ int wpre[16][8];
  __shared__ int cbase[8];
  const int tid = threadIdx.x, lane = tid & 63, w = tid >> 6;
  for (int i = tid; i < NE * CAP; i += 1024) idx[i] = T_TOK;
  if (tid < 8) running[tid] = 0;
  __syncthreads();
  for (int chunk = 0; chunk < T_TOK / 1024; ++chunk) {
    const int tok = chunk * 1024 + tid;
    const int e = top[tok];
    unsigned long long mymask = 0ull;
#pragma unroll
    for (int ee = 0; ee < 8; ++ee) {
      unsigned long long m = __ballot(e == ee);
      if (ee == e) mymask = m;
      if (lane == ee) wcnt[w][ee] = __builtin_popcountll(m);
    }
    const int rankw = __builtin_popcountll(mymask & ((1ull << lane) - 1ull));
    __syncthreads();
    if (tid < 8) {
      int s = 0;
#pragma unroll
      for (int ww = 0; ww < 16; ++ww) { wpre[ww][tid] = s; s += wcnt[ww][tid]; }
      cbase[tid] = running[tid];
      running[tid] += s;
    }
    __syncthreads();
    const int rank = cbase[e] + wpre[w][e] + rankw;
    if (rank < CAP) idx[e * CAP + rank] = tok;
  }
}

// ---------------------------------------------------------------------------
// Fused: xg image (bid < 512) + W1 image (bid >= 512).
// xg: tiles [e][mt256 4][kt 16][256 rows][8 gran], granule g at g^(row&7).
// W1: fp32 [k][n] -> fp16 tiles [n 256][k 64], granule g at g^(n&7),
//     tile index b = e*256 + nt*16 + kt (matches gemm1's reads).
// ---------------------------------------------------------------------------
__global__ __launch_bounds__(256) void xg_w1(
    const float* __restrict__ x, const int* __restrict__ idx,
    _Float16* __restrict__ xgimg,
    const float* __restrict__ W1, _Float16* __restrict__ w1img)
{
  __shared__ _Float16 sT[64 * 256];   // 32 KB (W1 path)
  const int tid = threadIdx.x, bid = blockIdx.x;
  if (bid < 512) {
    // ---- xg block (proven body) ----
    const int kt = bid & 15, mt = (bid >> 4) & 3, e = bid >> 6;
    const int tok = idx[e * CAP + mt * 256 + tid];
    _Float16* dst = xgimg + (size_t)((e * 4 + mt) * 16 + kt) * 16384 + (size_t)tid * 64;
    if (tok < T_TOK) {
      const f32x4* src = (const f32x4*)(x + (size_t)tok * DIM + kt * 64);
      f32x4 v[16];
#pragma unroll
      for (int i = 0; i < 16; ++i) v[i] = src[i];
#pragma unroll
      for (int g = 0; g < 8; ++g) {
        f16x8 h;
#pragma unroll
        for (int c = 0; c < 4; ++c) {
          h[c]     = (_Float16)v[2 * g][c];
          h[4 + c] = (_Float16)v[2 * g + 1][c];
        }
        *(f16x8*)(dst + ((g ^ (tid & 7)) * 8)) = h;
      }
    } else {
      f16x8 z = {};
#pragma unroll
      for (int g = 0; g < 8; ++g) *(f16x8*)(dst + g * 8) = z;
    }
    return;
  }
  // ---- W1 image block (proven w_image<256,16,16,FF> body) ----
  const int b = bid - 512;                      // 0..2047
  const int kt = b & 15, nt = (b >> 4) & 15, e = b >> 8;
  const float* src = W1 + (size_t)e * DIM * FF + (size_t)(kt * 64) * FF + nt * 256;
#pragma unroll
  for (int i = 0; i < 16; ++i) {
    const int q = i * 256 + tid;
    const int row = q >> 6, c4 = (q & 63) * 4;
    f32x4 u = *(const f32x4*)(src + (size_t)row * FF + c4);
    f16x4 h;
#pragma unroll
    for (int c = 0; c < 4; ++c) h[c] = (_Float16)u[c];
    *(f16x4*)&sT[row * 256 + c4] = h;
  }
  __syncthreads();
  _Float16* dst = w1img + (size_t)b * 16384;
  const int n = tid;
#pragma unroll
  for (int i = 0; i < 8; ++i) {
    const int g = i ^ (n & 7);
    f16x8 h;
#pragma unroll
    for (int j = 0; j < 8; ++j) h[j] = sT[(g * 8 + j) * 256 + n];
    *(f16x8*)(dst + (size_t)n * 64 + i * 8) = h;
  }
}

// ---------------------------------------------------------------------------
// Fused: gemm1 (bid%3==0, 2048 blocks) + W2 image (else, 4096 blocks),
// interleaved so short BW-bound W2 blocks soak idle HBM/slots alongside
// latency-bound gemm1 blocks.
// gemm1: hidden = relu(xg @ W1img + b1), 128x128xBK64, 256 thr (4 waves 2x2),
// single-buffer 32KB LDS, gload_lds, 4 blocks/CU (zero-tail rounds).
// W2 image: fp32 [k][n] -> fp16 tiles [n 128][k 64], g at g^(n&7),
// tile b = e*512 + nt*64 + kt (matches gemm2's reads).
// ---------------------------------------------------------------------------
__global__ __launch_bounds__(256, 4) void gemm1_w2(
    const _Float16* __restrict__ xg, const _Float16* __restrict__ w1img,
    const float* __restrict__ b1, _Float16* __restrict__ hidden,
    const float* __restrict__ W2, _Float16* __restrict__ w2img)
{
  __shared__ _Float16 As[8192];
  __shared__ _Float16 Bs[8192];
  const int tid = threadIdx.x;
  const int t3 = blockIdx.x / 3;
  const int r3 = blockIdx.x - t3 * 3;

  if (r3 != 0) {
    // ---- W2 image block ----
    const int b = 2 * t3 + (r3 - 1);            // 0..4095
    const int kt = b & 63, nt = (b >> 6) & 7, e = b >> 9;
    const float* src = W2 + (size_t)e * FF * DIM + (size_t)(kt * 64) * DIM + nt * 128;
    _Float16* sT = As;                          // [64][128] bounce
#pragma unroll
    for (int i = 0; i < 8; ++i) {
      const int q = i * 256 + tid;
      const int row = q >> 5, c4 = (q & 31) * 4;
      f32x4 u = *(const f32x4*)(src + (size_t)row * DIM + c4);
      f16x4 h;
#pragma unroll
      for (int c = 0; c < 4; ++c) h[c] = (_Float16)u[c];
      *(f16x4*)&sT[row * 128 + c4] = h;
    }
    __syncthreads();
    _Float16* dst = w2img + (size_t)b * 8192;
    const int n = tid & 127, gb = (tid >> 7) * 4;
#pragma unroll
    for (int i = 0; i < 4; ++i) {
      const int gpos = gb + i, g = gpos ^ (n & 7);
      f16x8 h;
#pragma unroll
      for (int j = 0; j < 8; ++j) h[j] = sT[(g * 8 + j) * 128 + n];
      *(f16x8*)(dst + (size_t)n * 64 + gpos * 8) = h;
    }
    return;
  }

  // ---- gemm1 block (round-6 proven body; gid = t3) ----
  const int lane = tid & 63, w = tid >> 6;
  const int wm = w >> 1, wn = w & 1;
  const int l15 = lane & 15, l4 = lane >> 4;
  const int e   = t3 >> 8;
  const int low = t3 & 255;
  const int nt  = ((low & 7) << 2) | ((low >> 3) & 3);  // 0..31
  const int mt  = low >> 5;                             // 0..7

  const _Float16* aSrc = xg + ((size_t)(e * 4 + (mt >> 1)) * 16) * 16384
                         + (size_t)(mt & 1) * 8192 + w * 2048 + lane * 8;
  const _Float16* bSrc = w1img + ((size_t)(e * 16 + (nt >> 1)) * 16) * 16384
                         + (size_t)(nt & 1) * 8192 + w * 2048 + lane * 8;

  f32x4 acc[4][4];
#pragma unroll
  for (int i = 0; i < 4; ++i)
#pragma unroll
    for (int j = 0; j < 4; ++j) acc[i][j] = (f32x4){0.f, 0.f, 0.f, 0.f};

  for (int kt = 0; kt < 16; ++kt) {
    __syncthreads();
#pragma unroll
    for (int i = 0; i < 4; ++i) {
      cp16(&As[w * 2048 + i * 512], aSrc + (size_t)kt * 16384 + i * 512);
      cp16(&Bs[w * 2048 + i * 512], bSrc + (size_t)kt * 16384 + i * 512);
    }
    __syncthreads();
#pragma unroll
    for (int ks = 0; ks < 2; ++ks) {
      const int gq = ks * 4 + l4;
      f16x8 af[4], bf[4];
#pragma unroll
      for (int fm = 0; fm < 4; ++fm) {
        const int m = wm * 64 + fm * 16 + l15;
        af[fm] = *(const f16x8*)&As[m * 64 + (gq ^ (m & 7)) * 8];
      }
#pragma unroll
      for (int fn = 0; fn < 4; ++fn) {
        const int n = wn * 64 + fn * 16 + l15;
        bf[fn] = *(const f16x8*)&Bs[n * 64 + (gq ^ (n & 7)) * 8];
      }
#pragma unroll
      for (int fm = 0; fm < 4; ++fm)
#pragma unroll
        for (int fn = 0; fn < 4; ++fn)
          acc[fm][fn] = __builtin_amdgcn_mfma_f32_16x16x32_f16(af[fm], bf[fn], acc[fm][fn], 0, 0, 0);
    }
  }

  // ---- epilogue: LDS-bounce transpose, relu(acc+b1) -> hidden image ----
  __syncthreads();
  float* sw = (float*)((w < 2) ? As : Bs) + (size_t)(w & 1) * 2048;  // 8KB/wave
  const int ftile = nt * 2 + wn;                 // 0..63
  const size_t tbase = ((size_t)((e * 8 + mt) * 64) + ftile) * 8192;
  const int fbase = nt * 128 + wn * 64;
#pragma unroll
  for (int fm = 0; fm < 4; ++fm) {
#pragma unroll
    for (int fn = 0; fn < 4; ++fn) {
      const int floc = fn * 16 + l15;
      const float bb = b1[e * FF + fbase + floc];
      f32x4 v;
#pragma unroll
      for (int r = 0; r < 4; ++r) v[r] = fmaxf(acc[fm][fn][r] + bb, 0.f);
      *(f32x4*)&sw[floc * 17 + l4 * 4] = v;
    }
    const int p = l15;
    const int mrow = wm * 64 + fm * 16 + p;
#pragma unroll
    for (int it = 0; it < 2; ++it) {
      const int g = it * 4 + l4;
      f16x8 h;
#pragma unroll
      for (int j = 0; j < 8; ++j) h[j] = (_Float16)sw[(g * 8 + j) * 17 + p];
      *(f16x8*)&hidden[tbase + (size_t)mrow * 64 + (g ^ (mrow & 7)) * 8] = h;
    }
  }
}

// ---------------------------------------------------------------------------
// GEMM2 (round-6 proven): out[tok] = (hidden @ W2img + b2) * topw.
// 128x128xBK64, 512 thr (8 waves 4Mx2N), 2 blocks/CU = 16 waves/CU.
// bid = e + 8*(nt*8 + mt): expert pinned to XCD.
// ---------------------------------------------------------------------------
__global__ __launch_bounds__(512, 4) void gemm2_big(
    const _Float16* __restrict__ hidden, const _Float16* __restrict__ w2img,
    const float* __restrict__ b2, const int* __restrict__ idx,
    const float* __restrict__ topw, float* __restrict__ out)
{
  __shared__ _Float16 As[8192];
  __shared__ _Float16 Bs[8192];
  const int tid = threadIdx.x, lane = tid & 63, w = tid >> 6;
  const int wm = w >> 1, wn = w & 1;               // wm 0..3, wn 0..1
  const int l15 = lane & 15, l4 = lane >> 4;
  const int bid = blockIdx.x;
  const int e  = bid & 7;
  const int s  = bid >> 3;       // 0..63
  const int nt = s >> 3;         // 0..7 (128-col D tile)
  const int mt = s & 7;          // 0..7 (128-row tile)

  const _Float16* aSrc = hidden + ((size_t)((e * 8 + mt) * 64)) * 8192 + w * 1024 + lane * 8;
  const _Float16* bSrc = w2img  + ((size_t)((e * 8 + nt) * 64)) * 8192 + w * 1024 + lane * 8;

  f32x4 acc[2][4];
#pragma unroll
  for (int i = 0; i < 2; ++i)
#pragma unroll
    for (int j = 0; j < 4; ++j) acc[i][j] = (f32x4){0.f, 0.f, 0.f, 0.f};

  for (int kt = 0; kt < 64; ++kt) {
    __syncthreads();
#pragma unroll
    for (int i = 0; i < 2; ++i) {
      cp16(&As[w * 1024 + i * 512], aSrc + (size_t)kt * 8192 + i * 512);
      cp16(&Bs[w * 1024 + i * 512], bSrc + (size_t)kt * 8192 + i * 512);
    }
    __syncthreads();
#pragma unroll
    for (int ks = 0; ks < 2; ++ks) {
      const int gq = ks * 4 + l4;
      f16x8 af[2], bf[4];
#pragma unroll
      for (int fm = 0; fm < 2; ++fm) {
        const int m = wm * 32 + fm * 16 + l15;
        af[fm] = *(const f16x8*)&As[m * 64 + (gq ^ (m & 7)) * 8];
      }
#pragma unroll
      for (int fn = 0; fn < 4; ++fn) {
        const int n = wn * 64 + fn * 16 + l15;
        bf[fn] = *(const f16x8*)&Bs[n * 64 + (gq ^ (n & 7)) * 8];
      }
#pragma unroll
      for (int fm = 0; fm < 2; ++fm)
#pragma unroll
        for (int fn = 0; fn < 4; ++fn)
          acc[fm][fn] = __builtin_amdgcn_mfma_f32_16x16x32_f16(af[fm], bf[fn], acc[fm][fn], 0, 0, 0);
    }
  }

  // epilogue: scatter (acc + b2) * topw to token rows
  int   toks[2][4];
  float wgts[2][4];
#pragma unroll
  for (int fm = 0; fm < 2; ++fm)
#pragma unroll
    for (int r = 0; r < 4; ++r) {
      const int row = mt * 128 + wm * 32 + fm * 16 + l4 * 4 + r;
      const int tk = idx[e * CAP + row];
      toks[fm][r] = tk;
      wgts[fm][r] = (tk < T_TOK) ? topw[tk] : 0.f;
    }
#pragma unroll
  for (int fn = 0; fn < 4; ++fn) {
    const int dcol = nt * 128 + wn * 64 + fn * 16 + l15;
    const float bb = b2[e * DIM + dcol];
#pragma unroll
    for (int fm = 0; fm < 2; ++fm)
#pragma unroll
      for (int r = 0; r < 4; ++r) {
        const int tk = toks[fm][r];
        if (tk < T_TOK)
          out[(size_t)tk * DIM + dcol] = (acc[fm][fn][r] + bb) * wgts[fm][r];
      }
  }
}

// ---------------------------------------------------------------------------
extern "C" void kernel_launch(void* const* d_in, const int* in_sizes, int n_in,
                              void* d_out, int out_size, void* d_ws, size_t ws_size,
                              hipStream_t stream)
{
  const float* x  = (const float*)d_in[0];
  const float* Wr = (const float*)d_in[1];
  const float* W1 = (const float*)d_in[2];
  const float* b1 = (const float*)d_in[3];
  const float* W2 = (const float*)d_in[4];
  const float* b2 = (const float*)d_in[5];
  float* out = (float*)d_out;
  char* ws = (char*)d_ws;

  const size_t HID  = 67108864ull;  // hidden image fp16
  const size_t WIMG = 67108864ull;  // W1 image; W2 image overwrites it is NOT
                                    // possible now -> W2 shares via timeline:
                                    // w1img live only during gemm1_w2; w2img
                                    // written during gemm1_w2. They must be
                                    // separate? No: w2img written while w1img
                                    // read -> separate halves NOT available.
                                    // => w2img reuses XG+spare? No. Use the
                                    // proven layout: w1img in WIMG, w2img in
                                    // a second region ONLY if ws allows; else
                                    // fall back to sequential conversion.
  const size_t XG   = 16777216ull;  // gathered-x image fp16

  _Float16* hidden = (_Float16*)ws;
  _Float16* w1img  = (_Float16*)(ws + HID);
  _Float16* xg     = (_Float16*)(ws + HID + WIMG);
  int*   idx  = (int*)(ws + HID + WIMG + XG);
  int*   top  = idx + 8192;
  float* topw = (float*)(top + 8192);
  // second weight-image region (needed because W1 image stays live while the
  // W2 image is produced inside gemm1_w2)
  _Float16* w2img = (_Float16*)(ws + HID + WIMG + XG + 3 * 32768ull);

  const size_t NEED_FUSED = HID + WIMG + XG + 3 * 32768ull + WIMG;

  hipMemsetAsync(d_out, 0, (size_t)T_TOK * DIM * sizeof(float), stream);
  moe_router<<<T_TOK / 16, 256, 0, stream>>>(x, Wr, top, topw);
  moe_scan<<<1, 1024, 0, stream>>>(top, idx);
  xg_w1<<<512 + 2048, 256, 0, stream>>>(x, idx, xg, W1, w1img);
  if (ws_size >= NEED_FUSED) {
    // fused path: W2 conversion interleaved into gemm1
    gemm1_w2<<<3 * 2048, 256, 0, stream>>>(xg, w1img, b1, hidden, W2, w2img);
    gemm2_big<<<NE * 8 * 8, 512, 0, stream>>>(hidden, w2img, b2, idx, topw, out);
  } else {
    // fallback: sequential W2 conversion into the W1 image region (round-6
    // proven ordering; gemm1 first, then overwrite w1img with w2 image)
    gemm1_w2<<<3 * 2048, 256, 0, stream>>>(xg, w1img, b1, hidden,
                                           W2, w1img /*unused until done*/);
    gemm2_big<<<NE * 8 * 8, 512, 0, stream>>>(hidden, w1img, b2, idx, topw, out);
  }
}

// Round 8
// 306.822 us; speedup vs baseline: 1.2210x; 1.0071x over previous
//
#include <hip/hip_runtime.h>
#include <hip/hip_bf16.h>
#include <hip/hip_fp16.h>

typedef _Float16 f16x8 __attribute__((ext_vector_type(8)));
typedef _Float16 f16x4 __attribute__((ext_vector_type(4)));
typedef float f32x4 __attribute__((ext_vector_type(4)));

#define T_TOK 8192
#define DIM   1024
#define FF    4096
#define NE    8
#define CAP   1024

// ---------------------------------------------------------------------------
// async global->LDS 16B copy. LDS dest = wave-uniform base + lane*16 (HW);
// global src is per-lane.
// ---------------------------------------------------------------------------
__device__ __forceinline__ void cp16(_Float16* lds, const _Float16* g) {
  __builtin_amdgcn_global_load_lds(
      (const __attribute__((address_space(1))) unsigned int*)(const void*)g,
      (__attribute__((address_space(3))) unsigned int*)(void*)lds, 16, 0, 0);
}

// ---------------------------------------------------------------------------
// Router (proven)
// ---------------------------------------------------------------------------
__global__ __launch_bounds__(256) void moe_router(
    const float* __restrict__ x, const float* __restrict__ Wr,
    int* __restrict__ top, float* __restrict__ topw)
{
  __shared__ float sWr[DIM * 9];
  const int tid = threadIdx.x;
  for (int i = tid; i < DIM * NE; i += 256) {
    int d = i >> 3, e = i & 7;
    sWr[d * 9 + e] = Wr[i];
  }
  __syncthreads();
  const int lane = tid & 63, w = tid >> 6;
  for (int t = 0; t < 4; ++t) {
    const int token = blockIdx.x * 16 + w * 4 + t;
    float acc[8] = {0.f, 0.f, 0.f, 0.f, 0.f, 0.f, 0.f, 0.f};
    for (int j = 0; j < 16; ++j) {
      float xv = x[(size_t)token * DIM + j * 64 + lane];
      const float* wr = &sWr[(j * 64 + lane) * 9];
#pragma unroll
      for (int e = 0; e < 8; ++e) acc[e] += xv * wr[e];
    }
#pragma unroll
    for (int e = 0; e < 8; ++e) {
#pragma unroll
      for (int off = 32; off > 0; off >>= 1)
        acc[e] += __shfl_xor(acc[e], off, 64);
    }
    if (lane == 0) {
      float m = acc[0];
#pragma unroll
      for (int e = 1; e < 8; ++e) m = fmaxf(m, acc[e]);
      float s = 0.f;
#pragma unroll
      for (int e = 0; e < 8; ++e) s += expf(acc[e] - m);
      int bi = 0; float bv = acc[0];
#pragma unroll
      for (int e = 1; e < 8; ++e) { if (acc[e] > bv) { bv = acc[e]; bi = e; } }
      top[token]  = bi;
      topw[token] = 1.0f / s;
    }
  }
}

// ---------------------------------------------------------------------------
// Order-preserving dispatch (proven, 1024 thr)
// ---------------------------------------------------------------------------
__global__ __launch_bounds__(1024) void moe_scan(
    const int* __restrict__ top, int* __restrict__ idx)
{
  __shared__ int running[8];
  __shared__ int wcnt[16][8];
  __shared__ int wpre[16][8];
  __shared__ int cbase[8];
  const int tid = threadIdx.x, lane = tid & 63, w = tid >> 6;
  for (int i = tid; i < NE * CAP; i += 1024) idx[i] = T_TOK;
  if (tid < 8) running[tid] = 0;
  __syncthreads();
  for (int chunk = 0; chunk < T_TOK / 1024; ++chunk) {
    const int tok = chunk * 1024 + tid;
    const int e = top[tok];
    unsigned long long mymask = 0ull;
#pragma unroll
    for (int ee = 0; ee < 8; ++ee) {
      unsigned long long m = __ballot(e == ee);
      if (ee == e) mymask = m;
      if (lane == ee) wcnt[w][ee] = __builtin_popcountll(m);
    }
    const int rankw = __builtin_popcountll(mymask & ((1ull << lane) - 1ull));
    __syncthreads();
    if (tid < 8) {
      int s = 0;
#pragma unroll
      for (int ww = 0; ww < 16; ++ww) { wpre[ww][tid] = s; s += wcnt[ww][tid]; }
      cbase[tid] = running[tid];
      running[tid] += s;
    }
    __syncthreads();
    const int rank = cbase[e] + wpre[w][e] + rankw;
    if (rank < CAP) idx[e * CAP + rank] = tok;
  }
}

// ---------------------------------------------------------------------------
// Fused: xg image (bid < 512) + W1 image (bid >= 512). (proven round 7)
// ---------------------------------------------------------------------------
__global__ __launch_bounds__(256) void xg_w1(
    const float* __restrict__ x, const int* __restrict__ idx,
    _Float16* __restrict__ xgimg,
    const float* __restrict__ W1, _Float16* __restrict__ w1img)
{
  __shared__ _Float16 sT[64 * 256];   // 32 KB (W1 path)
  const int tid = threadIdx.x, bid = blockIdx.x;
  if (bid < 512) {
    const int kt = bid & 15, mt = (bid >> 4) & 3, e = bid >> 6;
    const int tok = idx[e * CAP + mt * 256 + tid];
    _Float16* dst = xgimg + (size_t)((e * 4 + mt) * 16 + kt) * 16384 + (size_t)tid * 64;
    if (tok < T_TOK) {
      const f32x4* src = (const f32x4*)(x + (size_t)tok * DIM + kt * 64);
      f32x4 v[16];
#pragma unroll
      for (int i = 0; i < 16; ++i) v[i] = src[i];
#pragma unroll
      for (int g = 0; g < 8; ++g) {
        f16x8 h;
#pragma unroll
        for (int c = 0; c < 4; ++c) {
          h[c]     = (_Float16)v[2 * g][c];
          h[4 + c] = (_Float16)v[2 * g + 1][c];
        }
        *(f16x8*)(dst + ((g ^ (tid & 7)) * 8)) = h;
      }
    } else {
      f16x8 z = {};
#pragma unroll
      for (int g = 0; g < 8; ++g) *(f16x8*)(dst + g * 8) = z;
    }
    return;
  }
  const int b = bid - 512;                      // 0..2047
  const int kt = b & 15, nt = (b >> 4) & 15, e = b >> 8;
  const float* src = W1 + (size_t)e * DIM * FF + (size_t)(kt * 64) * FF + nt * 256;
#pragma unroll
  for (int i = 0; i < 16; ++i) {
    const int q = i * 256 + tid;
    const int row = q >> 6, c4 = (q & 63) * 4;
    f32x4 u = *(const f32x4*)(src + (size_t)row * FF + c4);
    f16x4 h;
#pragma unroll
    for (int c = 0; c < 4; ++c) h[c] = (_Float16)u[c];
    *(f16x4*)&sT[row * 256 + c4] = h;
  }
  __syncthreads();
  _Float16* dst = w1img + (size_t)b * 16384;
  const int n = tid;
#pragma unroll
  for (int i = 0; i < 8; ++i) {
    const int g = i ^ (n & 7);
    f16x8 h;
#pragma unroll
    for (int j = 0; j < 8; ++j) h[j] = sT[(g * 8 + j) * 256 + n];
    *(f16x8*)(dst + (size_t)n * 64 + i * 8) = h;
  }
}

// ---------------------------------------------------------------------------
// Fused: gemm1 (bid < 2048, round-6 proven map intact) + W2 image
// (bid >= 2048, backfills freed slots during gemm1's drain tail, soaking
// idle HBM BW without diluting gemm1's resident-slot L2 rectangles).
// ---------------------------------------------------------------------------
__global__ __launch_bounds__(256, 4) void gemm1_w2(
    const _Float16* __restrict__ xg, const _Float16* __restrict__ w1img,
    const float* __restrict__ b1, _Float16* __restrict__ hidden,
    const float* __restrict__ W2, _Float16* __restrict__ w2img)
{
  __shared__ _Float16 As[8192];
  __shared__ _Float16 Bs[8192];
  const int tid = threadIdx.x;
  const int bid = blockIdx.x;

  if (bid >= 2048) {
    // ---- W2 image block (proven round-7 body) ----
    const int b = bid - 2048;                   // 0..4095
    const int kt = b & 63, nt = (b >> 6) & 7, e = b >> 9;
    const float* src = W2 + (size_t)e * FF * DIM + (size_t)(kt * 64) * DIM + nt * 128;
    _Float16* sT = As;                          // [64][128] bounce
#pragma unroll
    for (int i = 0; i < 8; ++i) {
      const int q = i * 256 + tid;
      const int row = q >> 5, c4 = (q & 31) * 4;
      f32x4 u = *(const f32x4*)(src + (size_t)row * DIM + c4);
      f16x4 h;
#pragma unroll
      for (int c = 0; c < 4; ++c) h[c] = (_Float16)u[c];
      *(f16x4*)&sT[row * 128 + c4] = h;
    }
    __syncthreads();
    _Float16* dst = w2img + (size_t)b * 8192;
    const int n = tid & 127, gb = (tid >> 7) * 4;
#pragma unroll
    for (int i = 0; i < 4; ++i) {
      const int gpos = gb + i, g = gpos ^ (n & 7);
      f16x8 h;
#pragma unroll
      for (int j = 0; j < 8; ++j) h[j] = sT[(g * 8 + j) * 128 + n];
      *(f16x8*)(dst + (size_t)n * 64 + gpos * 8) = h;
    }
    return;
  }

  // ---- gemm1 block (round-6 proven body; logical id = bid directly) ----
  const int lane = tid & 63, w = tid >> 6;
  const int wm = w >> 1, wn = w & 1;
  const int l15 = lane & 15, l4 = lane >> 4;
  const int e   = bid >> 8;
  const int low = bid & 255;
  const int nt  = ((low & 7) << 2) | ((low >> 3) & 3);  // 0..31
  const int mt  = low >> 5;                             // 0..7

  const _Float16* aSrc = xg + ((size_t)(e * 4 + (mt >> 1)) * 16) * 16384
                         + (size_t)(mt & 1) * 8192 + w * 2048 + lane * 8;
  const _Float16* bSrc = w1img + ((size_t)(e * 16 + (nt >> 1)) * 16) * 16384
                         + (size_t)(nt & 1) * 8192 + w * 2048 + lane * 8;

  f32x4 acc[4][4];
#pragma unroll
  for (int i = 0; i < 4; ++i)
#pragma unroll
    for (int j = 0; j < 4; ++j) acc[i][j] = (f32x4){0.f, 0.f, 0.f, 0.f};

  for (int kt = 0; kt < 16; ++kt) {
    __syncthreads();
#pragma unroll
    for (int i = 0; i < 4; ++i) {
      cp16(&As[w * 2048 + i * 512], aSrc + (size_t)kt * 16384 + i * 512);
      cp16(&Bs[w * 2048 + i * 512], bSrc + (size_t)kt * 16384 + i * 512);
    }
    __syncthreads();
#pragma unroll
    for (int ks = 0; ks < 2; ++ks) {
      const int gq = ks * 4 + l4;
      f16x8 af[4], bf[4];
#pragma unroll
      for (int fm = 0; fm < 4; ++fm) {
        const int m = wm * 64 + fm * 16 + l15;
        af[fm] = *(const f16x8*)&As[m * 64 + (gq ^ (m & 7)) * 8];
      }
#pragma unroll
      for (int fn = 0; fn < 4; ++fn) {
        const int n = wn * 64 + fn * 16 + l15;
        bf[fn] = *(const f16x8*)&Bs[n * 64 + (gq ^ (n & 7)) * 8];
      }
#pragma unroll
      for (int fm = 0; fm < 4; ++fm)
#pragma unroll
        for (int fn = 0; fn < 4; ++fn)
          acc[fm][fn] = __builtin_amdgcn_mfma_f32_16x16x32_f16(af[fm], bf[fn], acc[fm][fn], 0, 0, 0);
    }
  }

  // ---- epilogue: LDS-bounce transpose, relu(acc+b1) -> hidden image ----
  __syncthreads();
  float* sw = (float*)((w < 2) ? As : Bs) + (size_t)(w & 1) * 2048;  // 8KB/wave
  const int ftile = nt * 2 + wn;                 // 0..63
  const size_t tbase = ((size_t)((e * 8 + mt) * 64) + ftile) * 8192;
  const int fbase = nt * 128 + wn * 64;
#pragma unroll
  for (int fm = 0; fm < 4; ++fm) {
#pragma unroll
    for (int fn = 0; fn < 4; ++fn) {
      const int floc = fn * 16 + l15;
      const float bb = b1[e * FF + fbase + floc];
      f32x4 v;
#pragma unroll
      for (int r = 0; r < 4; ++r) v[r] = fmaxf(acc[fm][fn][r] + bb, 0.f);
      *(f32x4*)&sw[floc * 17 + l4 * 4] = v;
    }
    const int p = l15;
    const int mrow = wm * 64 + fm * 16 + p;
#pragma unroll
    for (int it = 0; it < 2; ++it) {
      const int g = it * 4 + l4;
      f16x8 h;
#pragma unroll
      for (int j = 0; j < 8; ++j) h[j] = (_Float16)sw[(g * 8 + j) * 17 + p];
      *(f16x8*)&hidden[tbase + (size_t)mrow * 64 + (g ^ (mrow & 7)) * 8] = h;
    }
  }
}

// ---------------------------------------------------------------------------
// GEMM2 (round-6 proven): out[tok] = (hidden @ W2img + b2) * topw.
// 128x128xBK64, 512 thr (8 waves 4Mx2N), 2 blocks/CU = 16 waves/CU.
// bid = e + 8*(nt*8 + mt): expert pinned to XCD.
// ---------------------------------------------------------------------------
__global__ __launch_bounds__(512, 4) void gemm2_big(
    const _Float16* __restrict__ hidden, const _Float16* __restrict__ w2img,
    const float* __restrict__ b2, const int* __restrict__ idx,
    const float* __restrict__ topw, float* __restrict__ out)
{
  __shared__ _Float16 As[8192];
  __shared__ _Float16 Bs[8192];
  const int tid = threadIdx.x, lane = tid & 63, w = tid >> 6;
  const int wm = w >> 1, wn = w & 1;               // wm 0..3, wn 0..1
  const int l15 = lane & 15, l4 = lane >> 4;
  const int bid = blockIdx.x;
  const int e  = bid & 7;
  const int s  = bid >> 3;       // 0..63
  const int nt = s >> 3;         // 0..7 (128-col D tile)
  const int mt = s & 7;          // 0..7 (128-row tile)

  const _Float16* aSrc = hidden + ((size_t)((e * 8 + mt) * 64)) * 8192 + w * 1024 + lane * 8;
  const _Float16* bSrc = w2img  + ((size_t)((e * 8 + nt) * 64)) * 8192 + w * 1024 + lane * 8;

  f32x4 acc[2][4];
#pragma unroll
  for (int i = 0; i < 2; ++i)
#pragma unroll
    for (int j = 0; j < 4; ++j) acc[i][j] = (f32x4){0.f, 0.f, 0.f, 0.f};

  for (int kt = 0; kt < 64; ++kt) {
    __syncthreads();
#pragma unroll
    for (int i = 0; i < 2; ++i) {
      cp16(&As[w * 1024 + i * 512], aSrc + (size_t)kt * 8192 + i * 512);
      cp16(&Bs[w * 1024 + i * 512], bSrc + (size_t)kt * 8192 + i * 512);
    }
    __syncthreads();
#pragma unroll
    for (int ks = 0; ks < 2; ++ks) {
      const int gq = ks * 4 + l4;
      f16x8 af[2], bf[4];
#pragma unroll
      for (int fm = 0; fm < 2; ++fm) {
        const int m = wm * 32 + fm * 16 + l15;
        af[fm] = *(const f16x8*)&As[m * 64 + (gq ^ (m & 7)) * 8];
      }
#pragma unroll
      for (int fn = 0; fn < 4; ++fn) {
        const int n = wn * 64 + fn * 16 + l15;
        bf[fn] = *(const f16x8*)&Bs[n * 64 + (gq ^ (n & 7)) * 8];
      }
#pragma unroll
      for (int fm = 0; fm < 2; ++fm)
#pragma unroll
        for (int fn = 0; fn < 4; ++fn)
          acc[fm][fn] = __builtin_amdgcn_mfma_f32_16x16x32_f16(af[fm], bf[fn], acc[fm][fn], 0, 0, 0);
    }
  }

  // epilogue: scatter (acc + b2) * topw to token rows
  int   toks[2][4];
  float wgts[2][4];
#pragma unroll
  for (int fm = 0; fm < 2; ++fm)
#pragma unroll
    for (int r = 0; r < 4; ++r) {
      const int row = mt * 128 + wm * 32 + fm * 16 + l4 * 4 + r;
      const int tk = idx[e * CAP + row];
      toks[fm][r] = tk;
      wgts[fm][r] = (tk < T_TOK) ? topw[tk] : 0.f;
    }
#pragma unroll
  for (int fn = 0; fn < 4; ++fn) {
    const int dcol = nt * 128 + wn * 64 + fn * 16 + l15;
    const float bb = b2[e * DIM + dcol];
#pragma unroll
    for (int fm = 0; fm < 2; ++fm)
#pragma unroll
      for (int r = 0; r < 4; ++r) {
        const int tk = toks[fm][r];
        if (tk < T_TOK)
          out[(size_t)tk * DIM + dcol] = (acc[fm][fn][r] + bb) * wgts[fm][r];
      }
  }
}

// ---------------------------------------------------------------------------
extern "C" void kernel_launch(void* const* d_in, const int* in_sizes, int n_in,
                              void* d_out, int out_size, void* d_ws, size_t ws_size,
                              hipStream_t stream)
{
  const float* x  = (const float*)d_in[0];
  const float* Wr = (const float*)d_in[1];
  const float* W1 = (const float*)d_in[2];
  const float* b1 = (const float*)d_in[3];
  const float* W2 = (const float*)d_in[4];
  const float* b2 = (const float*)d_in[5];
  float* out = (float*)d_out;
  char* ws = (char*)d_ws;

  const size_t HID  = 67108864ull;  // hidden image fp16
  const size_t WIMG = 67108864ull;  // W1 image
  const size_t XG   = 16777216ull;  // gathered-x image fp16

  _Float16* hidden = (_Float16*)ws;
  _Float16* w1img  = (_Float16*)(ws + HID);
  _Float16* xg     = (_Float16*)(ws + HID + WIMG);
  int*   idx  = (int*)(ws + HID + WIMG + XG);
  int*   top  = idx + 8192;
  float* topw = (float*)(top + 8192);
  // second weight-image region (W1 image stays live while W2 image is made)
  _Float16* w2img = (_Float16*)(ws + HID + WIMG + XG + 3 * 32768ull);

  hipMemsetAsync(d_out, 0, (size_t)T_TOK * DIM * sizeof(float), stream);
  moe_router<<<T_TOK / 16, 256, 0, stream>>>(x, Wr, top, topw);
  moe_scan<<<1, 1024, 0, stream>>>(top, idx);
  xg_w1<<<512 + 2048, 256, 0, stream>>>(x, idx, xg, W1, w1img);
  gemm1_w2<<<2048 + 4096, 256, 0, stream>>>(xg, w1img, b1, hidden, W2, w2img);
  gemm2_big<<<NE * 8 * 8, 512, 0, stream>>>(hidden, w2img, b2, idx, topw, out);
}